// Round 1
// baseline (1680.296 us; speedup 1.0000x reference)
//
#include <hip/hip_runtime.h>
#include <hip/hip_bf16.h>

#define BB 4
#define SS 2048
#define DD 1024
#define HH 16
#define HD 64

typedef __attribute__((ext_vector_type(8))) __bf16 bf16x8;
typedef __attribute__((ext_vector_type(8))) unsigned short ushortx8;
typedef __attribute__((ext_vector_type(4))) unsigned short ushortx4;
typedef __attribute__((ext_vector_type(4))) float floatx4;

static __device__ __forceinline__ unsigned short bf16_of(float f) {
    union { float f; unsigned u; } v; v.f = f;
    // round-to-nearest-even
    unsigned r = (v.u + 0x7fffu + ((v.u >> 16) & 1u)) >> 16;
    return (unsigned short)r;
}

// ---------------- fp32 -> bf16 convert ----------------
__global__ __launch_bounds__(256) void cvt_bf16(const float* __restrict__ in,
                                                unsigned short* __restrict__ out) {
    size_t i = ((size_t)blockIdx.x * 256 + threadIdx.x) * 4;
    float4 f = *(const float4*)(in + i);
    ushortx4 s;
    s[0] = bf16_of(f.x); s[1] = bf16_of(f.y); s[2] = bf16_of(f.z); s[3] = bf16_of(f.w);
    *(ushortx4*)(out + i) = s;
}

// ---------------- GEMM  C[m,n] = sum_k A[m,k]*Bt[n,k] + bias[n]  ----------------
// M=8192, N=1024, K=1024. Tile: BM=64, BN=64, BK=64. 256 threads = 4 waves,
// wave w owns rows [w*16, w*16+16).
// MODE 0: store bf16 row-major [m, n]
// MODE 1: store bf16 head-transposed VT[b, h, d, s]  (m = b*S+s, n = h*64+d)
// MODE 2: store fp32 row-major with +resid[m,n]
template <int MODE>
__global__ __launch_bounds__(256) void gemm_bt(const unsigned short* __restrict__ A,
                                               const unsigned short* __restrict__ Bt,
                                               const float* __restrict__ bias,
                                               void* __restrict__ out,
                                               const float* __restrict__ resid) {
    __shared__ unsigned short As[64][72];
    __shared__ unsigned short Bs[64][72];
    const int m0 = blockIdx.y * 64;
    const int n0 = blockIdx.x * 64;
    const int tid = threadIdx.x;
    const int wave = tid >> 6, lane = tid & 63;
    const int quad = lane >> 4, tt = lane & 15;

    floatx4 acc[4];
#pragma unroll
    for (int i = 0; i < 4; ++i) { acc[i][0]=0.f; acc[i][1]=0.f; acc[i][2]=0.f; acc[i][3]=0.f; }

    for (int kk = 0; kk < 1024; kk += 64) {
#pragma unroll
        for (int t = 0; t < 2; ++t) {
            int c = tid + t * 256;
            int row = c >> 3, col8 = (c & 7) * 8;
            *(ushortx8*)&As[row][col8] = *(const ushortx8*)&A[(size_t)(m0 + row) * 1024 + kk + col8];
            *(ushortx8*)&Bs[row][col8] = *(const ushortx8*)&Bt[(size_t)(n0 + row) * 1024 + kk + col8];
        }
        __syncthreads();
#pragma unroll
        for (int ks = 0; ks < 2; ++ks) {
            bf16x8 af = *(const bf16x8*)&As[wave * 16 + tt][ks * 32 + quad * 8];
#pragma unroll
            for (int nt = 0; nt < 4; ++nt) {
                bf16x8 bf = *(const bf16x8*)&Bs[nt * 16 + tt][ks * 32 + quad * 8];
                acc[nt] = __builtin_amdgcn_mfma_f32_16x16x32_bf16(af, bf, acc[nt], 0, 0, 0);
            }
        }
        __syncthreads();
    }
#pragma unroll
    for (int nt = 0; nt < 4; ++nt) {
        int n = n0 + nt * 16 + tt;
        float bv = bias[n];
#pragma unroll
        for (int r = 0; r < 4; ++r) {
            int m = m0 + wave * 16 + quad * 4 + r;
            float v = acc[nt][r] + bv;
            if (MODE == 0) {
                ((unsigned short*)out)[(size_t)m * 1024 + n] = bf16_of(v);
            } else if (MODE == 1) {
                int b = m >> 11, s = m & 2047;
                int h = n >> 6, d = n & 63;
                ((unsigned short*)out)[((size_t)(b * HH + h) * HD + d) * SS + s] = bf16_of(v);
            } else {
                ((float*)out)[(size_t)m * 1024 + n] = v + resid[(size_t)m * 1024 + n];
            }
        }
    }
}

// ---------------- fused attention ----------------
// grid (S/64, H, B); block 256 = 4 waves; wave w owns q-rows [q0+w*16, +16).
// Pass 1: row sums of exp(QK^T/8). Pass 2: recompute, write normalized attn,
// accumulate ctx = P @ V via LDS round-trip of P.
__global__ __launch_bounds__(256) void attn_kernel(const unsigned short* __restrict__ Qb,
                                                   const unsigned short* __restrict__ Kb,
                                                   const unsigned short* __restrict__ VTb,
                                                   float* __restrict__ attn,
                                                   unsigned short* __restrict__ ctxb) {
    __shared__ unsigned short Qs[64][72];
    __shared__ unsigned short Ks[64][72];
    __shared__ unsigned short Vs[64][72];
    __shared__ unsigned short Ps[4][16][72];
    __shared__ float rinv_s[64];

    const int q0 = blockIdx.x * 64;
    const int h = blockIdx.y, b = blockIdx.z;
    const int tid = threadIdx.x;
    const int wave = tid >> 6, lane = tid & 63;
    const int quad = lane >> 4, tt = lane & 15;

    const size_t qkbase = (size_t)b * SS * DD + (size_t)h * HD;   // + s*DD + d
    const size_t vtbase = (size_t)(b * HH + h) * HD * SS;          // + d*SS + s

    // stage Q tile (reused by both passes)
#pragma unroll
    for (int t = 0; t < 2; ++t) {
        int c = tid + t * 256;
        int row = c >> 3, col8 = (c & 7) * 8;
        *(ushortx8*)&Qs[row][col8] = *(const ushortx8*)&Qb[qkbase + (size_t)(q0 + row) * DD + col8];
    }
    __syncthreads();
    bf16x8 a0 = *(const bf16x8*)&Qs[wave * 16 + tt][quad * 8];
    bf16x8 a1 = *(const bf16x8*)&Qs[wave * 16 + tt][32 + quad * 8];

    // ---- pass 1: row sums ----
    float sumacc[4] = {0.f, 0.f, 0.f, 0.f};
    for (int n0 = 0; n0 < SS; n0 += 64) {
#pragma unroll
        for (int t = 0; t < 2; ++t) {
            int c = tid + t * 256;
            int row = c >> 3, col8 = (c & 7) * 8;
            *(ushortx8*)&Ks[row][col8] = *(const ushortx8*)&Kb[qkbase + (size_t)(n0 + row) * DD + col8];
        }
        __syncthreads();
#pragma unroll
        for (int nt = 0; nt < 4; ++nt) {
            floatx4 sc; sc[0]=0.f; sc[1]=0.f; sc[2]=0.f; sc[3]=0.f;
            bf16x8 b0 = *(const bf16x8*)&Ks[nt * 16 + tt][quad * 8];
            bf16x8 b1 = *(const bf16x8*)&Ks[nt * 16 + tt][32 + quad * 8];
            sc = __builtin_amdgcn_mfma_f32_16x16x32_bf16(a0, b0, sc, 0, 0, 0);
            sc = __builtin_amdgcn_mfma_f32_16x16x32_bf16(a1, b1, sc, 0, 0, 0);
#pragma unroll
            for (int r = 0; r < 4; ++r) sumacc[r] += __expf(sc[r] * 0.125f);
        }
        __syncthreads();
    }
#pragma unroll
    for (int r = 0; r < 4; ++r) {
        float v = sumacc[r];
        v += __shfl_xor(v, 1, 64);
        v += __shfl_xor(v, 2, 64);
        v += __shfl_xor(v, 4, 64);
        v += __shfl_xor(v, 8, 64);
        if (tt == 0) rinv_s[wave * 16 + quad * 4 + r] = 1.0f / v;
    }
    __syncthreads();
    float rinv[4];
#pragma unroll
    for (int r = 0; r < 4; ++r) rinv[r] = rinv_s[wave * 16 + quad * 4 + r];

    // ---- pass 2: attn write + ctx accumulate ----
    floatx4 ctx[4];
#pragma unroll
    for (int i = 0; i < 4; ++i) { ctx[i][0]=0.f; ctx[i][1]=0.f; ctx[i][2]=0.f; ctx[i][3]=0.f; }

    for (int n0 = 0; n0 < SS; n0 += 64) {
#pragma unroll
        for (int t = 0; t < 2; ++t) {
            int c = tid + t * 256;
            int row = c >> 3, col8 = (c & 7) * 8;
            *(ushortx8*)&Ks[row][col8] = *(const ushortx8*)&Kb[qkbase + (size_t)(n0 + row) * DD + col8];
            *(ushortx8*)&Vs[row][col8] = *(const ushortx8*)&VTb[vtbase + (size_t)row * SS + n0 + col8];
        }
        __syncthreads();
#pragma unroll
        for (int nt = 0; nt < 4; ++nt) {
            floatx4 sc; sc[0]=0.f; sc[1]=0.f; sc[2]=0.f; sc[3]=0.f;
            bf16x8 b0 = *(const bf16x8*)&Ks[nt * 16 + tt][quad * 8];
            bf16x8 b1 = *(const bf16x8*)&Ks[nt * 16 + tt][32 + quad * 8];
            sc = __builtin_amdgcn_mfma_f32_16x16x32_bf16(a0, b0, sc, 0, 0, 0);
            sc = __builtin_amdgcn_mfma_f32_16x16x32_bf16(a1, b1, sc, 0, 0, 0);
#pragma unroll
            for (int r = 0; r < 4; ++r) {
                float p = __expf(sc[r] * 0.125f) * rinv[r];
                attn[((size_t)(b * HH + h) * SS + q0 + wave * 16 + quad * 4 + r) * SS
                     + n0 + nt * 16 + tt] = p;
                Ps[wave][quad * 4 + r][nt * 16 + tt] = bf16_of(p);
            }
        }
        // P (this wave's private LDS) @ V
#pragma unroll
        for (int ks = 0; ks < 2; ++ks) {
            bf16x8 pa = *(const bf16x8*)&Ps[wave][tt][ks * 32 + quad * 8];
#pragma unroll
            for (int dt = 0; dt < 4; ++dt) {
                bf16x8 vb = *(const bf16x8*)&Vs[dt * 16 + tt][ks * 32 + quad * 8];
                ctx[dt] = __builtin_amdgcn_mfma_f32_16x16x32_bf16(pa, vb, ctx[dt], 0, 0, 0);
            }
        }
        __syncthreads();
    }
#pragma unroll
    for (int dt = 0; dt < 4; ++dt) {
#pragma unroll
        for (int r = 0; r < 4; ++r) {
            int s = q0 + wave * 16 + quad * 4 + r;
            ctxb[((size_t)b * SS + s) * DD + h * HD + dt * 16 + tt] = bf16_of(ctx[dt][r]);
        }
    }
}

// ---------------- row LayerNorm (D=1024), one block per row ----------------
__global__ __launch_bounds__(256) void ln_kernel(const float* __restrict__ y,
                                                 const float* __restrict__ gamma,
                                                 const float* __restrict__ beta,
                                                 float* __restrict__ out) {
    const int row = blockIdx.x;
    const int tid = threadIdx.x;
    const int wave = tid >> 6, lane = tid & 63;
    const float* x = y + (size_t)row * DD;
    float4 v = *(const float4*)&x[tid * 4];
    float s = v.x + v.y + v.z + v.w;
    float sq = v.x * v.x + v.y * v.y + v.z * v.z + v.w * v.w;
#pragma unroll
    for (int m = 1; m < 64; m <<= 1) {
        s += __shfl_xor(s, m, 64);
        sq += __shfl_xor(sq, m, 64);
    }
    __shared__ float red[8];
    if (lane == 0) { red[wave] = s; red[4 + wave] = sq; }
    __syncthreads();
    s = red[0] + red[1] + red[2] + red[3];
    sq = red[4] + red[5] + red[6] + red[7];
    float mu = s * (1.0f / 1024.0f);
    float var = sq * (1.0f / 1024.0f) - mu * mu;
    float rs = rsqrtf(var + 1e-5f);
    float4 g = *(const float4*)&gamma[tid * 4];
    float4 be = *(const float4*)&beta[tid * 4];
    float4 o;
    o.x = (v.x - mu) * rs * g.x + be.x;
    o.y = (v.y - mu) * rs * g.y + be.y;
    o.z = (v.z - mu) * rs * g.z + be.z;
    o.w = (v.w - mu) * rs * g.w + be.w;
    *(float4*)&out[(size_t)row * DD + tid * 4] = o;
}

extern "C" void kernel_launch(void* const* d_in, const int* in_sizes, int n_in,
                              void* d_out, int out_size, void* d_ws, size_t ws_size,
                              hipStream_t stream) {
    const float* query = (const float*)d_in[0];
    const float* key_t = (const float*)d_in[1];
    const float* value = (const float*)d_in[2];
    const float* Wq = (const float*)d_in[3];
    const float* bq = (const float*)d_in[4];
    const float* Wk = (const float*)d_in[5];
    const float* bk = (const float*)d_in[6];
    const float* Wv = (const float*)d_in[7];
    const float* bv = (const float*)d_in[8];
    const float* Wo = (const float*)d_in[9];
    const float* bo = (const float*)d_in[10];
    const float* gamma = (const float*)d_in[11];
    const float* beta = (const float*)d_in[12];

    float* out = (float*)d_out;
    float* attn = out + (size_t)BB * SS * DD;   // 8,388,608 floats in

    const size_t NBIG = (size_t)BB * SS * DD;   // 8,388,608
    const size_t NW = (size_t)DD * DD;          // 1,048,576
    unsigned short* qb   = (unsigned short*)d_ws;
    unsigned short* kb   = qb + NBIG;
    unsigned short* vvb  = kb + NBIG;
    unsigned short* Qb   = vvb + NBIG;
    unsigned short* Kb   = Qb + NBIG;
    unsigned short* VTb  = Kb + NBIG;
    unsigned short* ctxb = VTb + NBIG;
    unsigned short* Wqb  = ctxb + NBIG;
    unsigned short* Wkb  = Wqb + NW;
    unsigned short* Wvb  = Wkb + NW;
    unsigned short* Wob  = Wvb + NW;
    float* ybuf = (float*)(Wob + NW);

    // converts
    cvt_bf16<<<dim3(NBIG / 1024), 256, 0, stream>>>(query, qb);
    cvt_bf16<<<dim3(NBIG / 1024), 256, 0, stream>>>(key_t, kb);
    cvt_bf16<<<dim3(NBIG / 1024), 256, 0, stream>>>(value, vvb);
    cvt_bf16<<<dim3(NW / 1024), 256, 0, stream>>>(Wq, Wqb);
    cvt_bf16<<<dim3(NW / 1024), 256, 0, stream>>>(Wk, Wkb);
    cvt_bf16<<<dim3(NW / 1024), 256, 0, stream>>>(Wv, Wvb);
    cvt_bf16<<<dim3(NW / 1024), 256, 0, stream>>>(Wo, Wob);

    // projections
    dim3 g(16, 128);
    gemm_bt<0><<<g, 256, 0, stream>>>(qb, Wqb, bq, (void*)Qb, nullptr);
    gemm_bt<0><<<g, 256, 0, stream>>>(kb, Wkb, bk, (void*)Kb, nullptr);
    gemm_bt<1><<<g, 256, 0, stream>>>(vvb, Wvb, bv, (void*)VTb, nullptr);

    // fused attention
    attn_kernel<<<dim3(SS / 64, HH, BB), 256, 0, stream>>>(Qb, Kb, VTb, attn, ctxb);

    // output projection + residual
    gemm_bt<2><<<g, 256, 0, stream>>>(ctxb, Wob, bo, (void*)ybuf, query);

    // layernorm
    ln_kernel<<<dim3(BB * SS), 256, 0, stream>>>(ybuf, gamma, beta, out);
}